// Round 1
// baseline (896.566 us; speedup 1.0000x reference)
//
#include <hip/hip_runtime.h>
#include <cmath>

#define RMAXF 5.0f
#define INV_AVG (1.0f/16.0f)
#define SQ4PI 3.5449077018110318f

__device__ __forceinline__ int l_of_lm(int lm){ return lm==0?0:(lm<4?1:(lm<9?2:3)); }

// Real sph harmonics l=0..3 (times sqrt(4pi)) of unit vector (x,y,z)
__device__ __forceinline__ void sph16(float x, float y, float z, float* Y){
  float x2=x*x, y2=y*y, z2=z*z;
  Y[0]=SQ4PI*0.28209479177387814f;
  Y[1]=SQ4PI*0.4886025119029199f*y;
  Y[2]=SQ4PI*0.4886025119029199f*z;
  Y[3]=SQ4PI*0.4886025119029199f*x;
  Y[4]=SQ4PI*1.0925484305920792f*x*y;
  Y[5]=SQ4PI*1.0925484305920792f*y*z;
  Y[6]=SQ4PI*0.31539156525252005f*(3.f*z2-1.f);
  Y[7]=SQ4PI*1.0925484305920792f*x*z;
  Y[8]=SQ4PI*0.5462742152960396f*(x2-y2);
  Y[9]=SQ4PI*0.5900435899266435f*y*(3.f*x2-y2);
  Y[10]=SQ4PI*2.890611442640554f*x*y*z;
  Y[11]=SQ4PI*0.4570457994644658f*y*(5.f*z2-1.f);
  Y[12]=SQ4PI*0.3731763325901154f*z*(5.f*z2-3.f);
  Y[13]=SQ4PI*0.4570457994644658f*x*(5.f*z2-1.f);
  Y[14]=SQ4PI*1.445305721320277f*z*(x2-y2);
  Y[15]=SQ4PI*0.5900435899266435f*x*(x2-3.f*y2);
}

// radial basis ef[8] = bess*fcut and d(ef)/dr. Caller guarantees r < RMAX.
__device__ __forceinline__ void radial(float r, bool want_d, float* ef, float* def){
  const float PI_ = 3.14159265358979323846f;
  const float c = 0.6324555320336759f; // sqrt(2/5)
  float xr = r*(1.0f/RMAXF);
  float x2=xr*xr, x3=x2*xr, x5=x3*x2, x6=x5*xr, x7=x6*xr, x8=x7*xr;
  float fcut = 1.f - 28.f*x6 + 48.f*x7 - 21.f*x8;
  float om = 1.f - xr;
  float dfcut = -168.f*x5*om*om*(1.0f/RMAXF);
  float invr = 1.f/r;
  #pragma unroll
  for(int n=1;n<=8;n++){
    float a = (float)n*PI_*(1.0f/RMAXF);
    float ar = a*r;
    float s = sinf(ar), co = cosf(ar);
    float b = c*s*invr;
    ef[n-1] = b*fcut;
    if(want_d) def[n-1] = c*(a*co - s*invr)*invr*fcut + b*dfcut;
  }
}

// ---------------- node embed: h = attrs @ W_embed, e0 atomic per graph ----
__global__ __launch_bounds__(64) void embed_k(
    const float* __restrict__ attrs, const float* __restrict__ W_embed,
    const float* __restrict__ ae, const int* __restrict__ batch,
    float* __restrict__ h, float* __restrict__ e_acc, int N)
{
  int n = blockIdx.x;
  if(n >= N) return;
  int k = threadIdx.x;
  float acc = 0.f;
  #pragma unroll
  for(int s=0;s<10;s++) acc += attrs[n*10+s]*W_embed[s*64+k];
  h[(size_t)n*64+k] = acc;
  if(k==0){
    float e0 = 0.f;
    #pragma unroll
    for(int s=0;s<10;s++) e0 += attrs[n*10+s]*ae[s];
    atomicAdd(&e_acc[batch[n]*2+0], e0);
  }
}

// ---------------- transpose W_r2 -> W2T[k][j] = W_r2[j][k] ----------------
__global__ void tr_k(const float* __restrict__ W_r2, float* __restrict__ W2T){
  int i = threadIdx.x + blockIdx.x*blockDim.x;
  if(i < 4096){ int j = i>>6, k = i&63; W2T[k*64+j] = W_r2[i]; }
}

// ---------------- edge forward: scatter A[recv][lm][k] --------------------
__global__ __launch_bounds__(256) void edge_fwd(
    const float* __restrict__ pos, const float* __restrict__ shifts,
    const int* __restrict__ eidx, const float* __restrict__ h,
    const float* __restrict__ W_r1, const float* __restrict__ W_r2,
    float* __restrict__ A, int E)
{
  int e = (blockIdx.x*blockDim.x + threadIdx.x) >> 6;
  int lane = threadIdx.x & 63;
  int ws = threadIdx.x >> 6;
  __shared__ float s_silu[4][64];
  if(e >= E) return;
  int snd = eidx[e], rcv = eidx[E+e];
  float vx = pos[rcv*3+0]-pos[snd*3+0]+shifts[e*3+0];
  float vy = pos[rcv*3+1]-pos[snd*3+1]+shifts[e*3+1];
  float vz = pos[rcv*3+2]-pos[snd*3+2]+shifts[e*3+2];
  float r2 = vx*vx+vy*vy+vz*vz + 1e-12f;
  float r = sqrtf(r2);
  if(r >= RMAXF) return;   // fcut==0 -> w==0 -> m==0, whole wave skips
  float invr = 1.f/r;
  float ux=vx*invr, uy=vy*invr, uz=vz*invr;
  float Y[16]; sph16(ux,uy,uz,Y);
  float ef[8]; radial(r,false,ef,nullptr);
  // t = ef @ W_r1, one output per lane
  float t = 0.f;
  #pragma unroll
  for(int n=0;n<8;n++) t += ef[n]*W_r1[n*64+lane];
  float sig = 1.f/(1.f+expf(-t));
  float sl = t*sig;
  s_silu[ws][lane] = sl;
  // w = silu @ W_r2
  float w = 0.f;
  for(int j=0;j<64;j++) w += s_silu[ws][j]*W_r2[j*64+lane];
  float wh = w * h[(size_t)snd*64+lane] * INV_AVG;
  float* Ab = A + (size_t)rcv*1024 + lane;
  #pragma unroll
  for(int lm=0;lm<16;lm++) atomicAdd(Ab + lm*64, wh*Y[lm]);
}

// ---------------- node: Am, s, B, node_e, and gA (in-place over A) --------
__global__ __launch_bounds__(256) void node_k(
    float* __restrict__ A,              // [N][16][64], overwritten with gA
    const float* __restrict__ W_mix,    // [4][64][64]
    const float* __restrict__ W_prod,   // [3][64]
    const float* __restrict__ w_ro,     // [64]
    const int* __restrict__ batch, float* __restrict__ e_acc, int N)
{
  int n = blockIdx.x;
  if(n >= N) return;
  int c = threadIdx.x & 63;
  int lmg = threadIdx.x >> 6;
  __shared__ float sA[16][64];
  __shared__ float sG[16][64];
  __shared__ float sS[4][64];
  __shared__ float sSf[64];
  __shared__ float sA0[64];
  for(int i=threadIdx.x;i<1024;i+=256) sA[i>>6][i&63] = A[(size_t)n*1024+i];
  __syncthreads();
  float am[4];
  float part = 0.f;
  #pragma unroll
  for(int tix=0;tix<4;tix++){
    int lm = lmg*4+tix;
    const float* Wl = W_mix + l_of_lm(lm)*4096;
    float acc = 0.f;
    for(int k=0;k<64;k++) acc += sA[lm][k]*Wl[k*64+c];
    am[tix] = acc; part += acc*acc;
  }
  sS[lmg][c] = part;
  __syncthreads();
  if(lmg==0){
    sSf[c] = sS[0][c]+sS[1][c]+sS[2][c]+sS[3][c];
    sA0[c] = am[0];
  }
  __syncthreads();
  float s = sSf[c], a0 = sA0[c];
  float wp0 = W_prod[c], wp1 = W_prod[64+c], wp2 = W_prod[128+c], wr = w_ro[c];
  // node energy (wave 0 only)
  if(lmg==0){
    float B = wp0*a0 + wp1*s + wp2*a0*s;
    float v = B*wr;
    #pragma unroll
    for(int off=32; off; off>>=1) v += __shfl_xor(v, off, 64);
    if(c==0) atomicAdd(&e_acc[batch[n]*2+1], v);
  }
  // gAm
  float gs = wr*(wp1 + wp2*a0);  // d node_e / d s[c]
  #pragma unroll
  for(int tix=0;tix<4;tix++){
    int lm = lmg*4+tix;
    float g = gs*2.f*am[tix];
    if(lm==0) g += wr*(wp0 + wp2*s);
    sG[lm][c] = g;
  }
  __syncthreads();
  // gA[k][lm] = sum_c gAm[c][lm]*W_mix[l][k][c]; thread handles k=c slot
  int k = c;
  #pragma unroll
  for(int tix=0;tix<4;tix++){
    int lm = lmg*4+tix;
    const float* Wl = W_mix + l_of_lm(lm)*4096 + k*64;
    float acc = 0.f;
    for(int cc=0;cc<64;cc++) acc += sG[lm][cc]*Wl[cc];
    A[(size_t)n*1024 + lm*64 + k] = acc;
  }
}

// ---------------- edge backward: forces ------------------------------------
__global__ __launch_bounds__(256) void edge_bwd(
    const float* __restrict__ pos, const float* __restrict__ shifts,
    const int* __restrict__ eidx, const float* __restrict__ h,
    const float* __restrict__ W_r1, const float* __restrict__ W_r2,
    const float* __restrict__ W2T, const float* __restrict__ gA,
    float* __restrict__ forces, int E)
{
  int e = (blockIdx.x*blockDim.x + threadIdx.x) >> 6;
  int lane = threadIdx.x & 63;
  int ws = threadIdx.x >> 6;
  __shared__ float s_silu[4][64];
  __shared__ float s_gw[4][64];
  if(e >= E) return;
  int snd = eidx[e], rcv = eidx[E+e];
  float vx = pos[rcv*3+0]-pos[snd*3+0]+shifts[e*3+0];
  float vy = pos[rcv*3+1]-pos[snd*3+1]+shifts[e*3+1];
  float vz = pos[rcv*3+2]-pos[snd*3+2]+shifts[e*3+2];
  float r2 = vx*vx+vy*vy+vz*vz + 1e-12f;
  float r = sqrtf(r2);
  if(r >= RMAXF) return;   // entire gradient vanishes
  float invr = 1.f/r;
  float x=vx*invr, y=vy*invr, z=vz*invr;
  float Y[16]; sph16(x,y,z,Y);
  float ef[8], def[8]; radial(r,true,ef,def);
  float t = 0.f;
  #pragma unroll
  for(int n=0;n<8;n++) t += ef[n]*W_r1[n*64+lane];
  float sig = 1.f/(1.f+expf(-t));
  float sl = t*sig;
  s_silu[ws][lane] = sl;
  float w = 0.f;
  for(int j=0;j<64;j++) w += s_silu[ws][j]*W_r2[j*64+lane];
  float hk = h[(size_t)snd*64+lane];
  float wh = w*hk;
  // gm[k][lm]
  const float* gb = gA + (size_t)rcv*1024 + lane;
  float gm[16];
  #pragma unroll
  for(int lm=0;lm<16;lm++) gm[lm] = gb[lm*64]*INV_AVG;
  // gw[k] = hk * sum_lm gm*Y
  float gw = 0.f;
  #pragma unroll
  for(int lm=0;lm<16;lm++) gw += gm[lm]*Y[lm];
  gw *= hk;
  // gY[lm] = sum_k gm[k][lm]*wh[k]  (butterfly over 64 lanes)
  float gY[16];
  #pragma unroll
  for(int lm=0;lm<16;lm++){
    float v = gm[lm]*wh;
    #pragma unroll
    for(int off=32; off; off>>=1) v += __shfl_xor(v, off, 64);
    gY[lm] = v;
  }
  // g_silu[j] = sum_k gw[k]*W_r2[j][k]  -> via W2T coalesced
  s_gw[ws][lane] = gw;
  float gsil = 0.f;
  for(int k=0;k<64;k++) gsil += s_gw[ws][k]*W2T[k*64+lane];
  float gt = gsil * sig*(1.f + t*(1.f-sig));
  // g_ef[n] = sum_j gt[j]*W_r1[n][j]
  float gef[8];
  #pragma unroll
  for(int n=0;n<8;n++){
    float v = gt*W_r1[n*64+lane];
    #pragma unroll
    for(int off=32; off; off>>=1) v += __shfl_xor(v, off, 64);
    gef[n] = v;
  }
  float gr = 0.f;
  #pragma unroll
  for(int n=0;n<8;n++) gr += gef[n]*def[n];
  // g_u from gY (analytic dY/du), lane-redundant
  const float c1=0.4886025119029199f, c2=1.0925484305920792f, c3=0.31539156525252005f;
  const float c4=0.5462742152960396f, c5=0.5900435899266435f, c6=2.890611442640554f;
  const float c7=0.4570457994644658f, c8=0.3731763325901154f, c9=1.445305721320277f;
  float x2=x*x, y2=y*y, z2=z*z;
  float fz1 = 5.f*z2-1.f;
  float gx = c1*gY[3] + c2*(y*gY[4] + z*gY[7]) + 2.f*c4*x*gY[8]
           + 6.f*c5*x*y*gY[9] + c6*y*z*gY[10] + c7*fz1*gY[13]
           + 2.f*c9*x*z*gY[14] + 3.f*c5*(x2-y2)*gY[15];
  float gy = c1*gY[1] + c2*(x*gY[4] + z*gY[5]) - 2.f*c4*y*gY[8]
           + 3.f*c5*(x2-y2)*gY[9] + c6*x*z*gY[10] + c7*fz1*gY[11]
           - 2.f*c9*y*z*gY[14] - 6.f*c5*x*y*gY[15];
  float gz = c1*gY[2] + c2*(y*gY[5] + x*gY[7]) + 6.f*c3*z*gY[6]
           + c6*x*y*gY[10] + 10.f*c7*y*z*gY[11] + c8*(15.f*z2-3.f)*gY[12]
           + 10.f*c7*x*z*gY[13] + c9*(x2-y2)*gY[14];
  gx *= SQ4PI; gy *= SQ4PI; gz *= SQ4PI;
  // g_vec = gr*u + (g_u - u (u.g_u))/r
  float udot = x*gx + y*gy + z*gz;
  float gvx = gr*x + (gx - udot*x)*invr;
  float gvy = gr*y + (gy - udot*y)*invr;
  float gvz = gr*z + (gz - udot*z)*invr;
  if(lane==0){
    // dE/dpos[recv] = +gvec, dE/dpos[send] = -gvec; forces = -grad
    atomicAdd(&forces[rcv*3+0], -gvx);
    atomicAdd(&forces[rcv*3+1], -gvy);
    atomicAdd(&forces[rcv*3+2], -gvz);
    atomicAdd(&forces[snd*3+0],  gvx);
    atomicAdd(&forces[snd*3+1],  gvy);
    atomicAdd(&forces[snd*3+2],  gvz);
  }
}

// ---------------- finalize ---------------------------------------------
__global__ void fin_k(const float* __restrict__ e_acc, float* __restrict__ out, int G){
  int g = threadIdx.x;
  if(g < G){
    float e0 = e_acc[2*g], e1 = e_acc[2*g+1];
    out[g] = e0+e1;
    out[G + 2*g] = e0;
    out[G + 2*g+1] = e1;
  }
}

extern "C" void kernel_launch(void* const* d_in, const int* in_sizes, int n_in,
                              void* d_out, int out_size, void* d_ws, size_t ws_size,
                              hipStream_t stream) {
  const float* positions  = (const float*)d_in[0];
  const float* node_attrs = (const float*)d_in[1];
  const float* shifts     = (const float*)d_in[2];
  const float* W_embed    = (const float*)d_in[3];
  const float* at_en      = (const float*)d_in[4];
  const float* W_r1       = (const float*)d_in[5];
  const float* W_r2       = (const float*)d_in[6];
  const float* W_mix      = (const float*)d_in[7];
  const float* W_prod     = (const float*)d_in[8];
  const float* w_ro       = (const float*)d_in[9];
  const int*   edge_index = (const int*)d_in[10];
  const int*   batch      = (const int*)d_in[11];

  int N = in_sizes[0]/3;
  int E = in_sizes[10]/2;
  int G = (out_size - 3*N)/3;

  float* out = (float*)d_out;
  float* A    = (float*)d_ws;                 // N*1024
  float* h    = A + (size_t)N*1024;           // N*64
  float* W2T  = h + (size_t)N*64;             // 4096
  float* eacc = W2T + 4096;                   // 2G

  hipMemsetAsync(d_out, 0, (size_t)out_size*sizeof(float), stream);
  hipMemsetAsync(A, 0, (size_t)N*1024*sizeof(float), stream);
  hipMemsetAsync(eacc, 0, (size_t)2*G*sizeof(float), stream);

  embed_k<<<N, 64, 0, stream>>>(node_attrs, W_embed, at_en, batch, h, eacc, N);
  tr_k<<<16, 256, 0, stream>>>(W_r2, W2T);
  edge_fwd<<<(E+3)/4, 256, 0, stream>>>(positions, shifts, edge_index, h, W_r1, W_r2, A, E);
  node_k<<<N, 256, 0, stream>>>(A, W_mix, W_prod, w_ro, batch, eacc, N);
  edge_bwd<<<(E+3)/4, 256, 0, stream>>>(positions, shifts, edge_index, h, W_r1, W_r2, W2T, A, out + 3*G, E);
  fin_k<<<1, 64, 0, stream>>>(eacc, out, G);
}

// Round 2
// 575.086 us; speedup vs baseline: 1.5590x; 1.5590x over previous
//
#include <hip/hip_runtime.h>
#include <cmath>

#define RMAXF 5.0f
#define INV_AVG (1.0f/16.0f)
#define SQ4PI 3.5449077018110318f

// Real sph harmonics l=0..3 (times sqrt(4pi)) of unit vector (x,y,z)
__device__ __forceinline__ void sph16(float x, float y, float z, float* Y){
  float x2=x*x, y2=y*y, z2=z*z;
  Y[0]=SQ4PI*0.28209479177387814f;
  Y[1]=SQ4PI*0.4886025119029199f*y;
  Y[2]=SQ4PI*0.4886025119029199f*z;
  Y[3]=SQ4PI*0.4886025119029199f*x;
  Y[4]=SQ4PI*1.0925484305920792f*x*y;
  Y[5]=SQ4PI*1.0925484305920792f*y*z;
  Y[6]=SQ4PI*0.31539156525252005f*(3.f*z2-1.f);
  Y[7]=SQ4PI*1.0925484305920792f*x*z;
  Y[8]=SQ4PI*0.5462742152960396f*(x2-y2);
  Y[9]=SQ4PI*0.5900435899266435f*y*(3.f*x2-y2);
  Y[10]=SQ4PI*2.890611442640554f*x*y*z;
  Y[11]=SQ4PI*0.4570457994644658f*y*(5.f*z2-1.f);
  Y[12]=SQ4PI*0.3731763325901154f*z*(5.f*z2-3.f);
  Y[13]=SQ4PI*0.4570457994644658f*x*(5.f*z2-1.f);
  Y[14]=SQ4PI*1.445305721320277f*z*(x2-y2);
  Y[15]=SQ4PI*0.5900435899266435f*x*(x2-3.f*y2);
}

// radial basis ef[8] = bess*fcut and d(ef)/dr. Caller guarantees r < RMAX.
__device__ __forceinline__ void radial(float r, bool want_d, float* ef, float* def){
  const float PI_ = 3.14159265358979323846f;
  const float c = 0.6324555320336759f; // sqrt(2/5)
  float xr = r*(1.0f/RMAXF);
  float x2=xr*xr, x3=x2*xr, x5=x3*x2, x6=x5*xr, x7=x6*xr, x8=x7*xr;
  float fcut = 1.f - 28.f*x6 + 48.f*x7 - 21.f*x8;
  float om = 1.f - xr;
  float dfcut = -168.f*x5*om*om*(1.0f/RMAXF);
  float invr = 1.f/r;
  #pragma unroll
  for(int n=1;n<=8;n++){
    float a = (float)n*PI_*(1.0f/RMAXF);
    float ar = a*r;
    float s = sinf(ar), co = cosf(ar);
    float b = c*s*invr;
    ef[n-1] = b*fcut;
    if(want_d) def[n-1] = c*(a*co - s*invr)*invr*fcut + b*dfcut;
  }
}

// ---------------- node embed: h = attrs @ W_embed, e0 atomic per graph ----
__global__ __launch_bounds__(64) void embed_k(
    const float* __restrict__ attrs, const float* __restrict__ W_embed,
    const float* __restrict__ ae, const int* __restrict__ batch,
    float* __restrict__ h, float* __restrict__ e_acc, int N)
{
  int n = blockIdx.x;
  if(n >= N) return;
  int k = threadIdx.x;
  float acc = 0.f;
  #pragma unroll
  for(int s=0;s<10;s++) acc += attrs[n*10+s]*W_embed[s*64+k];
  h[(size_t)n*64+k] = acc;
  if(k==0){
    float e0 = 0.f;
    #pragma unroll
    for(int s=0;s<10;s++) e0 += attrs[n*10+s]*ae[s];
    atomicAdd(&e_acc[batch[n]*2+0], e0);
  }
}

// ---------------- transpose W_r2 -> W2T[k][j] = W_r2[j][k] ----------------
__global__ void tr_k(const float* __restrict__ W_r2, float* __restrict__ W2T){
  int i = threadIdx.x + blockIdx.x*blockDim.x;
  if(i < 4096){ int j = i>>6, k = i&63; W2T[k*64+j] = W_r2[i]; }
}

// ---------------- edge compaction: survivors (r < RMAX) -------------------
__global__ __launch_bounds__(256) void compact_k(
    const float* __restrict__ pos, const float* __restrict__ shifts,
    const int* __restrict__ eidx, int* __restrict__ nsel,
    int* __restrict__ elist, int E)
{
  int e = blockIdx.x*256 + threadIdx.x;
  bool keep = false;
  if(e < E){
    int snd = eidx[e], rcv = eidx[E+e];
    float vx = pos[rcv*3+0]-pos[snd*3+0]+shifts[e*3+0];
    float vy = pos[rcv*3+1]-pos[snd*3+1]+shifts[e*3+1];
    float vz = pos[rcv*3+2]-pos[snd*3+2]+shifts[e*3+2];
    float r2 = vx*vx+vy*vy+vz*vz + 1e-12f;
    keep = (r2 < RMAXF*RMAXF);
  }
  unsigned long long m = __ballot(keep);
  int lane = threadIdx.x & 63;
  int base = 0;
  if(lane == 0 && m) base = atomicAdd(nsel, __popcll(m));
  base = __shfl(base, 0, 64);
  if(keep){
    int off = __popcll(m & ((1ull<<lane)-1ull));
    elist[base+off] = e;
  }
}

// ---------------- edge forward: scatter A[recv][lm][k] --------------------
__global__ __launch_bounds__(256) void edge_fwd(
    const float* __restrict__ pos, const float* __restrict__ shifts,
    const int* __restrict__ eidx, const float* __restrict__ h,
    const float* __restrict__ W_r1, const float* __restrict__ W_r2,
    const int* __restrict__ nsel, const int* __restrict__ elist,
    float* __restrict__ A, int E)
{
  int ws = threadIdx.x >> 6;
  int widx = blockIdx.x*4 + ws;
  int lane = threadIdx.x & 63;
  __shared__ float s_silu[4][64];
  if(widx >= *nsel) return;
  int e = elist[widx];
  int snd = eidx[e], rcv = eidx[E+e];
  float vx = pos[rcv*3+0]-pos[snd*3+0]+shifts[e*3+0];
  float vy = pos[rcv*3+1]-pos[snd*3+1]+shifts[e*3+1];
  float vz = pos[rcv*3+2]-pos[snd*3+2]+shifts[e*3+2];
  float r2 = vx*vx+vy*vy+vz*vz + 1e-12f;
  float r = sqrtf(r2);
  float invr = 1.f/r;
  float ux=vx*invr, uy=vy*invr, uz=vz*invr;
  float Y[16]; sph16(ux,uy,uz,Y);
  float ef[8]; radial(r,false,ef,nullptr);
  float t = 0.f;
  #pragma unroll
  for(int n=0;n<8;n++) t += ef[n]*W_r1[n*64+lane];
  float sig = 1.f/(1.f+expf(-t));
  s_silu[ws][lane] = t*sig;
  float w = 0.f;
  for(int j=0;j<64;j++) w += s_silu[ws][j]*W_r2[j*64+lane];
  float wh = w * h[(size_t)snd*64+lane] * INV_AVG;
  float* Ab = A + (size_t)rcv*1024 + lane;
  #pragma unroll
  for(int lm=0;lm<16;lm++) atomicAdd(Ab + lm*64, wh*Y[lm]);
}

// ---------------- node: Am, s, B, node_e, and gA (in-place over A) --------
// Persistent blocks; W_mix staged in LDS col-major with XOR swizzle.
// sW[l][c][k'] where k' = k ^ ((c&7)<<2)  (16B-granular XOR -> fwd b128 reads
// hit the 8-cyc bank floor; bwd per-lane reads are stride-1-permuted, free).
__global__ __launch_bounds__(256) void node_k(
    float* __restrict__ A,              // [N][16][64], overwritten with gA
    const float* __restrict__ W_mix,    // [4][64][64]
    const float* __restrict__ W_prod,   // [3][64]
    const float* __restrict__ w_ro,     // [64]
    const int* __restrict__ batch, float* __restrict__ e_acc, int N)
{
  __shared__ float sW[16384];
  __shared__ float sA[1024];
  __shared__ float sG[1024];
  __shared__ float sS[4][64];
  __shared__ float sSf[64];
  __shared__ float sA0[64];

  const int tid = threadIdx.x;
  const int c = tid & 63;
  const int lmg = tid >> 6;
  const int swz = (c & 7) << 2;

  // stage W_mix once per block (col-major + swizzle)
  for(int i = tid; i < 16384; i += 256){
    int l = i >> 12, k = (i >> 6) & 63, cc = i & 63;
    sW[l*4096 + cc*64 + (k ^ ((cc&7)<<2))] = W_mix[i];
  }

  const float wp0 = W_prod[c], wp1 = W_prod[64+c], wp2 = W_prod[128+c], wr = w_ro[c];
  // each lm-group needs at most 2 distinct l: lA (tix0), lB (tix1-3)
  const int lA = (lmg==0)?0:((lmg<3)?2:3);
  const int lB = (lmg==0)?1:((lmg==1)?2:3);
  const float* wBa = &sW[lA*4096 + c*64];
  const float* wBb = &sW[lB*4096 + c*64];
  const float* aB0 = &sA[(lmg*4+0)*64];
  const float* aB1 = &sA[(lmg*4+1)*64];
  const float* aB2 = &sA[(lmg*4+2)*64];
  const float* aB3 = &sA[(lmg*4+3)*64];
  float* gB0 = &sG[(lmg*4+0)*64];
  float* gB1 = &sG[(lmg*4+1)*64];
  float* gB2 = &sG[(lmg*4+2)*64];
  float* gB3 = &sG[(lmg*4+3)*64];

  for(int n = blockIdx.x; n < N; n += gridDim.x){
    // load A tile (covers W staging on first iteration via the sync below)
    reinterpret_cast<float4*>(sA)[tid] =
        reinterpret_cast<const float4*>(A + (size_t)n*1024)[tid];
    __syncthreads();

    // forward: am[lm][c] = sum_k sA[lm][k] * W[l][k][c]
    float am0=0.f, am1=0.f, am2=0.f, am3=0.f;
    #pragma unroll
    for(int kb=0; kb<16; kb++){
      int ko = (kb*4) ^ swz;
      float4 wa = *reinterpret_cast<const float4*>(wBa + ko);
      float4 wb = *reinterpret_cast<const float4*>(wBb + ko);
      float4 a0 = *reinterpret_cast<const float4*>(aB0 + kb*4);
      float4 a1 = *reinterpret_cast<const float4*>(aB1 + kb*4);
      float4 a2 = *reinterpret_cast<const float4*>(aB2 + kb*4);
      float4 a3 = *reinterpret_cast<const float4*>(aB3 + kb*4);
      am0 += a0.x*wa.x + a0.y*wa.y + a0.z*wa.z + a0.w*wa.w;
      am1 += a1.x*wb.x + a1.y*wb.y + a1.z*wb.z + a1.w*wb.w;
      am2 += a2.x*wb.x + a2.y*wb.y + a2.z*wb.z + a2.w*wb.w;
      am3 += a3.x*wb.x + a3.y*wb.y + a3.z*wb.z + a3.w*wb.w;
    }
    float part = am0*am0 + am1*am1 + am2*am2 + am3*am3;
    sS[lmg][c] = part;
    __syncthreads();
    if(lmg==0){
      sSf[c] = sS[0][c]+sS[1][c]+sS[2][c]+sS[3][c];
      sA0[c] = am0;
    }
    __syncthreads();
    float s_ = sSf[c], a0_ = sA0[c];
    if(lmg==0){
      float B = wp0*a0_ + wp1*s_ + wp2*a0_*s_;
      float v = B*wr;
      #pragma unroll
      for(int off=32; off; off>>=1) v += __shfl_xor(v, off, 64);
      if(c==0) atomicAdd(&e_acc[batch[n]*2+1], v);
    }
    float gs = wr*(wp1 + wp2*a0_);
    {
      float g0 = gs*2.f*am0;
      if(lmg==0) g0 += wr*(wp0 + wp2*s_);
      gB0[c] = g0;
      gB1[c] = gs*2.f*am1;
      gB2[c] = gs*2.f*am2;
      gB3[c] = gs*2.f*am3;
    }
    __syncthreads();

    // backward: gA[lm][k=c] = sum_cc sG[lm][cc] * W[l][k][cc]
    float ga0=0.f, ga1=0.f, ga2=0.f, ga3=0.f;
    #pragma unroll
    for(int cb=0; cb<16; cb++){
      float g0[4], g1[4], g2[4], g3[4];
      *reinterpret_cast<float4*>(g0) = *reinterpret_cast<const float4*>(gB0 + cb*4);
      *reinterpret_cast<float4*>(g1) = *reinterpret_cast<const float4*>(gB1 + cb*4);
      *reinterpret_cast<float4*>(g2) = *reinterpret_cast<const float4*>(gB2 + cb*4);
      *reinterpret_cast<float4*>(g3) = *reinterpret_cast<const float4*>(gB3 + cb*4);
      #pragma unroll
      for(int j=0;j<4;j++){
        int cc = cb*4 + j;
        int sidx = cc*64 + (c ^ ((cc&7)<<2));
        float wa = sW[lA*4096 + sidx];
        float wb = sW[lB*4096 + sidx];
        ga0 += wa*g0[j];
        ga1 += wb*g1[j];
        ga2 += wb*g2[j];
        ga3 += wb*g3[j];
      }
    }
    float* dst = A + (size_t)n*1024 + (size_t)lmg*256 + c;
    dst[0]   = ga0;
    dst[64]  = ga1;
    dst[128] = ga2;
    dst[192] = ga3;
    __syncthreads();   // protect sA/sG from next-iteration overwrite
  }
}

// ---------------- edge backward: forces ------------------------------------
__global__ __launch_bounds__(256) void edge_bwd(
    const float* __restrict__ pos, const float* __restrict__ shifts,
    const int* __restrict__ eidx, const float* __restrict__ h,
    const float* __restrict__ W_r1, const float* __restrict__ W_r2,
    const float* __restrict__ W2T, const float* __restrict__ gA,
    const int* __restrict__ nsel, const int* __restrict__ elist,
    float* __restrict__ forces, int E)
{
  int ws = threadIdx.x >> 6;
  int widx = blockIdx.x*4 + ws;
  int lane = threadIdx.x & 63;
  __shared__ float s_silu[4][64];
  __shared__ float s_gw[4][64];
  if(widx >= *nsel) return;
  int e = elist[widx];
  int snd = eidx[e], rcv = eidx[E+e];
  float vx = pos[rcv*3+0]-pos[snd*3+0]+shifts[e*3+0];
  float vy = pos[rcv*3+1]-pos[snd*3+1]+shifts[e*3+1];
  float vz = pos[rcv*3+2]-pos[snd*3+2]+shifts[e*3+2];
  float r2 = vx*vx+vy*vy+vz*vz + 1e-12f;
  float r = sqrtf(r2);
  float invr = 1.f/r;
  float x=vx*invr, y=vy*invr, z=vz*invr;
  float Y[16]; sph16(x,y,z,Y);
  float ef[8], def[8]; radial(r,true,ef,def);
  float t = 0.f;
  #pragma unroll
  for(int n=0;n<8;n++) t += ef[n]*W_r1[n*64+lane];
  float sig = 1.f/(1.f+expf(-t));
  s_silu[ws][lane] = t*sig;
  float w = 0.f;
  for(int j=0;j<64;j++) w += s_silu[ws][j]*W_r2[j*64+lane];
  float hk = h[(size_t)snd*64+lane];
  float wh = w*hk;
  const float* gb = gA + (size_t)rcv*1024 + lane;
  float gm[16];
  #pragma unroll
  for(int lm=0;lm<16;lm++) gm[lm] = gb[lm*64]*INV_AVG;
  float gw = 0.f;
  #pragma unroll
  for(int lm=0;lm<16;lm++) gw += gm[lm]*Y[lm];
  gw *= hk;
  float gY[16];
  #pragma unroll
  for(int lm=0;lm<16;lm++){
    float v = gm[lm]*wh;
    #pragma unroll
    for(int off=32; off; off>>=1) v += __shfl_xor(v, off, 64);
    gY[lm] = v;
  }
  s_gw[ws][lane] = gw;
  float gsil = 0.f;
  for(int k=0;k<64;k++) gsil += s_gw[ws][k]*W2T[k*64+lane];
  float gt = gsil * sig*(1.f + t*(1.f-sig));
  float gef[8];
  #pragma unroll
  for(int n=0;n<8;n++){
    float v = gt*W_r1[n*64+lane];
    #pragma unroll
    for(int off=32; off; off>>=1) v += __shfl_xor(v, off, 64);
    gef[n] = v;
  }
  float gr = 0.f;
  #pragma unroll
  for(int n=0;n<8;n++) gr += gef[n]*def[n];
  const float c1=0.4886025119029199f, c2=1.0925484305920792f, c3=0.31539156525252005f;
  const float c4=0.5462742152960396f, c5=0.5900435899266435f, c6=2.890611442640554f;
  const float c7=0.4570457994644658f, c8=0.3731763325901154f, c9=1.445305721320277f;
  float x2=x*x, y2=y*y, z2=z*z;
  float fz1 = 5.f*z2-1.f;
  float gx = c1*gY[3] + c2*(y*gY[4] + z*gY[7]) + 2.f*c4*x*gY[8]
           + 6.f*c5*x*y*gY[9] + c6*y*z*gY[10] + c7*fz1*gY[13]
           + 2.f*c9*x*z*gY[14] + 3.f*c5*(x2-y2)*gY[15];
  float gy = c1*gY[1] + c2*(x*gY[4] + z*gY[5]) - 2.f*c4*y*gY[8]
           + 3.f*c5*(x2-y2)*gY[9] + c6*x*z*gY[10] + c7*fz1*gY[11]
           - 2.f*c9*y*z*gY[14] - 6.f*c5*x*y*gY[15];
  float gz = c1*gY[2] + c2*(y*gY[5] + x*gY[7]) + 6.f*c3*z*gY[6]
           + c6*x*y*gY[10] + 10.f*c7*y*z*gY[11] + c8*(15.f*z2-3.f)*gY[12]
           + 10.f*c7*x*z*gY[13] + c9*(x2-y2)*gY[14];
  gx *= SQ4PI; gy *= SQ4PI; gz *= SQ4PI;
  float udot = x*gx + y*gy + z*gz;
  float gvx = gr*x + (gx - udot*x)*invr;
  float gvy = gr*y + (gy - udot*y)*invr;
  float gvz = gr*z + (gz - udot*z)*invr;
  if(lane==0){
    atomicAdd(&forces[rcv*3+0], -gvx);
    atomicAdd(&forces[rcv*3+1], -gvy);
    atomicAdd(&forces[rcv*3+2], -gvz);
    atomicAdd(&forces[snd*3+0],  gvx);
    atomicAdd(&forces[snd*3+1],  gvy);
    atomicAdd(&forces[snd*3+2],  gvz);
  }
}

// ---------------- finalize ---------------------------------------------
__global__ void fin_k(const float* __restrict__ e_acc, float* __restrict__ out, int G){
  int g = threadIdx.x;
  if(g < G){
    float e0 = e_acc[2*g], e1 = e_acc[2*g+1];
    out[g] = e0+e1;
    out[G + 2*g] = e0;
    out[G + 2*g+1] = e1;
  }
}

extern "C" void kernel_launch(void* const* d_in, const int* in_sizes, int n_in,
                              void* d_out, int out_size, void* d_ws, size_t ws_size,
                              hipStream_t stream) {
  const float* positions  = (const float*)d_in[0];
  const float* node_attrs = (const float*)d_in[1];
  const float* shifts     = (const float*)d_in[2];
  const float* W_embed    = (const float*)d_in[3];
  const float* at_en      = (const float*)d_in[4];
  const float* W_r1       = (const float*)d_in[5];
  const float* W_r2       = (const float*)d_in[6];
  const float* W_mix      = (const float*)d_in[7];
  const float* W_prod     = (const float*)d_in[8];
  const float* w_ro       = (const float*)d_in[9];
  const int*   edge_index = (const int*)d_in[10];
  const int*   batch      = (const int*)d_in[11];

  int N = in_sizes[0]/3;
  int E = in_sizes[10]/2;
  int G = (out_size - 3*N)/3;

  float* out  = (float*)d_out;
  float* A    = (float*)d_ws;                 // N*1024
  float* h    = A + (size_t)N*1024;           // N*64
  float* W2T  = h + (size_t)N*64;             // 4096
  float* eacc = W2T + 4096;                   // 2G
  int*   nsel = (int*)(eacc + 2*G);           // 1
  int*   elist= nsel + 1;                     // E

  hipMemsetAsync(d_out, 0, (size_t)out_size*sizeof(float), stream);
  hipMemsetAsync(A, 0, (size_t)N*1024*sizeof(float), stream);
  hipMemsetAsync(eacc, 0, ((size_t)2*G + 1)*sizeof(float), stream); // eacc + nsel

  embed_k<<<N, 64, 0, stream>>>(node_attrs, W_embed, at_en, batch, h, eacc, N);
  tr_k<<<16, 256, 0, stream>>>(W_r2, W2T);
  compact_k<<<(E+255)/256, 256, 0, stream>>>(positions, shifts, edge_index, nsel, elist, E);
  edge_fwd<<<(E+3)/4, 256, 0, stream>>>(positions, shifts, edge_index, h, W_r1, W_r2, nsel, elist, A, E);
  node_k<<<512, 256, 0, stream>>>(A, W_mix, W_prod, w_ro, batch, eacc, N);
  edge_bwd<<<(E+3)/4, 256, 0, stream>>>(positions, shifts, edge_index, h, W_r1, W_r2, W2T, A, nsel, elist, out + 3*G, E);
  fin_k<<<1, 64, 0, stream>>>(eacc, out, G);
}